// Round 5
// baseline (70.802 us; speedup 1.0000x reference)
//
#include <hip/hip_runtime.h>
#include <hip/hip_bf16.h>
#include <math.h>

// Problem: x[N=16,T=128,V=64,F=16] fp32, a[F=16] fp32.
// score[n,i,j] = (1/T) * sum_t sum_f a[f]*|x[n,t,i,f]-x[n,t,j,f]|
// e = exp(relu(score)); out[n,i,j] = e[n,i,j] / sum_i e[n,i,j]   (column norm)
//
// Measured context (R1-R4): the timed window contains a mandatory ~41 us
// harness poison-fill of the 256 MiB d_ws (82% HBM peak) + ~3 us input
// restore. Controllable kernel budget is ~25 us of the ~70 us total.
// HW facts learned: (1) uniform-address ds_read costs full DS-pipe
// throughput -> B operand from global (1-line L1 broadcast), not LDS.
// (2) lane-stride-64B global loads cost ~32 lines/instr in TA -> A operand
// must go through an LDS transpose (coalesced stage, pitch-20 b128 reads,
// 0 bank conflicts measured).

#define Nn 16
#define Tt 128
#define Vv 64
#define Ff 16
#define CHUNKS 16   // T split into 16 chunks of 8
#define TC 8
#define JSPLIT 4    // j split into 4 groups of 16 per block
#define JPW 4       // j's per wave (4 waves x 4 j = 16 j per block)
#define PITCH 20    // LDS row pitch: 80 B -> b128 reads hit all banks evenly

// ---------------- Kernel 1: partial weighted-L1 scores per t-chunk ----------
// grid = (CHUNKS, Nn, JSPLIT) = 1024 blocks, block 256, LDS 40 KB
// -> 4 blocks/CU, 4 waves/SIMD, <=128 VGPRs.
// ws layout: [n][j][c][i] fp32 (4 MB) -- column-contiguous for kernel 2.
__global__ __launch_bounds__(256, 4) void gls_scores(const float* __restrict__ x,
                                                     const float* __restrict__ a,
                                                     float* __restrict__ ws) {
    __shared__ float xs[TC * Vv * PITCH];   // 40 KB

    const int c   = blockIdx.x;
    const int n   = blockIdx.y;
    const int z   = blockIdx.z;
    const int tid = threadIdx.x;
    const int i   = tid & 63;
    const int w   = __builtin_amdgcn_readfirstlane(tid >> 6);
    const int j0  = z * (Vv / JSPLIT) + w * JPW;   // wave-uniform

    // stage x[n, c*8..c*8+7, :, :]: 2048 float4, lane-contiguous (coalesced)
    const float* xnc = x + (size_t)(n * Tt + c * TC) * (Vv * Ff);
    const float4* xg = (const float4*)xnc;
#pragma unroll
    for (int k = 0; k < 8; ++k) {
        const int f4  = tid + k * 256;
        const float4 val = xg[f4];
        const int tl  = f4 >> 8;
        const int v   = (f4 >> 2) & 63;
        const int f   = (f4 & 3) << 2;
        *(float4*)&xs[(tl * Vv + v) * PITCH + f] = val;
    }

    float af[Ff];
#pragma unroll
    for (int f = 0; f < Ff; ++f) af[f] = a[f];   // uniform -> SGPRs

    __syncthreads();

    float acc[JPW] = {0.f, 0.f, 0.f, 0.f};

#pragma unroll
    for (int tt = 0; tt < TC; ++tt) {
        const float* xi = &xs[(tt * Vv + i) * PITCH];        // conflict-free b128
        const float4 A0 = *(const float4*)(xi);
        const float4 A1 = *(const float4*)(xi + 4);
        const float4 A2 = *(const float4*)(xi + 8);
        const float4 A3 = *(const float4*)(xi + 12);
        const float* xtg = xnc + tt * (Vv * Ff);             // global, uniform
#pragma unroll
        for (int jj = 0; jj < JPW; ++jj) {
            const float* xb = xtg + (j0 + jj) * Ff;
            const float4 B0 = *(const float4*)(xb + 0);
            const float4 B1 = *(const float4*)(xb + 4);
            const float4 B2 = *(const float4*)(xb + 8);
            const float4 B3 = *(const float4*)(xb + 12);
            float s = acc[jj];
            s = fmaf(fabsf(A0.x - B0.x), af[0],  s);
            s = fmaf(fabsf(A0.y - B0.y), af[1],  s);
            s = fmaf(fabsf(A0.z - B0.z), af[2],  s);
            s = fmaf(fabsf(A0.w - B0.w), af[3],  s);
            s = fmaf(fabsf(A1.x - B1.x), af[4],  s);
            s = fmaf(fabsf(A1.y - B1.y), af[5],  s);
            s = fmaf(fabsf(A1.z - B1.z), af[6],  s);
            s = fmaf(fabsf(A1.w - B1.w), af[7],  s);
            s = fmaf(fabsf(A2.x - B2.x), af[8],  s);
            s = fmaf(fabsf(A2.y - B2.y), af[9],  s);
            s = fmaf(fabsf(A2.z - B2.z), af[10], s);
            s = fmaf(fabsf(A2.w - B2.w), af[11], s);
            s = fmaf(fabsf(A3.x - B3.x), af[12], s);
            s = fmaf(fabsf(A3.y - B3.y), af[13], s);
            s = fmaf(fabsf(A3.z - B3.z), af[14], s);
            s = fmaf(fabsf(A3.w - B3.w), af[15], s);
            acc[jj] = s;
        }
    }

    // ws[n][j][c][i] — lane-i contiguous => coalesced 256B stores
#pragma unroll
    for (int jj = 0; jj < JPW; ++jj)
        ws[(((size_t)n * Vv + j0 + jj) * CHUNKS + c) * Vv + i] = acc[jj];
}

// ---------------- Kernel 2: chunk-reduce + exp(relu) + column-normalize -----
// grid = (Nn, 16), block 256 (4 waves), wave = one (n,j) column.
// Column partials are 4 KB contiguous -> 4 dwordx4 per lane, then float4
// shfl-butterfly over lane-bits {4,5} finishes the c-sum; exp; column-sum
// via component-add + shfl_xor{1,2,4,8}; exactly one store per lane.
__global__ __launch_bounds__(256) void gls_norm(const float* __restrict__ ws,
                                                float* __restrict__ out) {
    const int n   = blockIdx.x;
    const int jq  = blockIdx.y;
    const int tid = threadIdx.x;
    const int l   = tid & 63;
    const int w   = tid >> 6;
    const int j   = jq * 4 + w;          // wave-uniform column

    const float4* p = (const float4*)(ws + ((size_t)n * Vv + j) * (CHUNKS * Vv));

    // lane l, load k: float4 index l + 64k -> c = (l>>4) + 4k, i-quad = (l&15)*4
    float4 s = {0.f, 0.f, 0.f, 0.f};
#pragma unroll
    for (int k = 0; k < 4; ++k) {
        const float4 v = p[l + 64 * k];
        s.x += v.x; s.y += v.y; s.z += v.z; s.w += v.w;
    }
    // finish c-sum: lanes differing in bits 4,5 hold the other c's of this quad
#pragma unroll
    for (int m = 16; m < 64; m <<= 1) {
        s.x += __shfl_xor(s.x, m, 64);
        s.y += __shfl_xor(s.y, m, 64);
        s.z += __shfl_xor(s.z, m, 64);
        s.w += __shfl_xor(s.w, m, 64);
    }

    float e[4];
    e[0] = expf(fmaxf(s.x * (1.0f / (float)Tt), 0.0f));
    e[1] = expf(fmaxf(s.y * (1.0f / (float)Tt), 0.0f));
    e[2] = expf(fmaxf(s.z * (1.0f / (float)Tt), 0.0f));
    e[3] = expf(fmaxf(s.w * (1.0f / (float)Tt), 0.0f));

    // column total: sum over the 16 i-quads (lane bits 0..3)
    float tot = e[0] + e[1] + e[2] + e[3];
#pragma unroll
    for (int m = 1; m < 16; m <<= 1) tot += __shfl_xor(tot, m, 64);
    const float r = 1.0f / tot;

    // one store per lane: i = (l&15)*4 + (l>>4)  (covers 0..63 uniquely)
    const int iq = (l & 15) * 4;
    const int q  = l >> 4;
    out[((size_t)n * Vv + iq + q) * Vv + j] = e[q] * r;
}

extern "C" void kernel_launch(void* const* d_in, const int* in_sizes, int n_in,
                              void* d_out, int out_size, void* d_ws, size_t ws_size,
                              hipStream_t stream) {
    const float* x = (const float*)d_in[0];   // [16,128,64,16]
    const float* a = (const float*)d_in[1];   // [16,1]
    float* out = (float*)d_out;               // [16,64,64]
    float* ws  = (float*)d_ws;                // 4 MB used

    dim3 g1(CHUNKS, Nn, JSPLIT);
    gls_scores<<<g1, 256, 0, stream>>>(x, a, ws);
    dim3 g2(Nn, 16);
    gls_norm<<<g2, 256, 0, stream>>>(ws, out);
}